// Round 13
// baseline (300.875 us; speedup 1.0000x reference)
//
#include <hip/hip_runtime.h>
#include <hip/hip_bf16.h>
#include <cstdint>

// B=64, N=1024, L=512, D=512, T=2, P=512, K_top=30
// out: rows [0,65536) hx ; [65536,131072) hv tiled ; then 1024*30 topk idx (float)
// NOTE: k_final launched TWICE this round as a timing probe (idempotent writes).

typedef float f32x4 __attribute__((ext_vector_type(4)));
typedef __bf16 bf16x8 __attribute__((ext_vector_type(8)));
typedef short short8 __attribute__((ext_vector_type(8)));
typedef short short4v __attribute__((ext_vector_type(4)));

__device__ __forceinline__ short f2bf(float f) {
  __hip_bfloat16 h = __float2bfloat16(f);   // native RNE cvt
  return *reinterpret_cast<short*>(&h);
}
__device__ __forceinline__ float bf2f(short s) {
  union { unsigned u; float f; } x; x.u = ((unsigned)(unsigned short)s) << 16;
  return x.f;
}

#define LDSG(gp, lp) __builtin_amdgcn_global_load_lds(                     \
    (const __attribute__((address_space(1))) void*)(gp),                   \
    (__attribute__((address_space(3))) void*)(lp), 16, 0, 0)

// ---------------- prep: [0,256) transpose W ; [256,272) emb col-stats ----------------
__global__ __launch_bounds__(256) void k_prep(
    const float* __restrict__ Wx, const float* __restrict__ Wv,
    const float* __restrict__ emb,
    short* __restrict__ Wxt, short* __restrict__ Wvt,
    float* __restrict__ pstatsE) {
  __shared__ float t[64][65];
  int bid = blockIdx.x, tid = threadIdx.x;
  if (bid < 256) {
    int z = bid >> 6, tile = bid & 63;
    const float* W = (z < 2) ? (Wx + (long)z * 262144) : (Wv + (long)(z - 2) * 262144);
    short* Wt = (z < 2) ? (Wxt + (long)z * 262144) : (Wvt + (long)(z - 2) * 262144);
    int r0 = (tile >> 3) * 64, c0 = (tile & 7) * 64;
    int lr = tid >> 4, lc = (tid & 15) * 4;
#pragma unroll
    for (int p = 0; p < 4; ++p) {
      f32x4 v = *(const f32x4*)(W + (long)(r0 + lr + p * 16) * 512 + c0 + lc);
#pragma unroll
      for (int j = 0; j < 4; ++j) t[lr + p * 16][lc + j] = v[j];
    }
    __syncthreads();
    int wr = (tid & 15) * 4;
    int wc = tid >> 4;
#pragma unroll
    for (int p = 0; p < 4; ++p) {
      int c = wc + p * 16;
      short4v o;
#pragma unroll
      for (int j = 0; j < 4; ++j) o[j] = f2bf(t[wr + j][c]);
      *(short4v*)(Wt + (long)(c0 + c) * 512 + r0 + wr) = o;
    }
  } else {
    int chunk = bid - 256;  // 16 chunks x 64 rows
    const float* p = emb + (long)chunk * 64 * 512;
#pragma unroll
    for (int i = 0; i < 2; ++i) {
      int c = tid + i * 256;
      float s = 0.f, q = 0.f;
#pragma unroll 4
      for (int r = 0; r < 64; ++r) {
        float v = p[(long)r * 512 + c];
        s += v; q = fmaf(v, v, q);
      }
      pstatsE[((long)chunk * 2 + 0) * 512 + c] = s;
      pstatsE[((long)chunk * 2 + 1) * 512 + c] = q;
    }
  }
}

// ---------------- v = BN(emb): wave-per-row; vbf bf16; vn normalized ----------------
__global__ __launch_bounds__(256) void k_compute_v(const float* __restrict__ emb,
                                                   const float* __restrict__ pstatsE,
                                                   const float* __restrict__ gamma,
                                                   const float* __restrict__ beta,
                                                   short* __restrict__ vbf,
                                                   float* __restrict__ vn) {
  __shared__ float ssl[1024];
  int tid = threadIdx.x, wv = tid >> 6, lane = tid & 63;
#pragma unroll
  for (int i = 0; i < 2; ++i) {
    int c = tid + i * 256;
    float s = 0.f, q = 0.f;
#pragma unroll
    for (int k = 0; k < 16; ++k) {
      s += pstatsE[((long)k * 2 + 0) * 512 + c];
      q += pstatsE[((long)k * 2 + 1) * 512 + c];
    }
    float mu = s * (1.f / 1024.f);
    float var = fmaxf(q * (1.f / 1024.f) - mu * mu, 0.f);
    float scale = rsqrtf(var + 1e-5f) * gamma[c];
    ssl[c] = scale;
    ssl[512 + c] = beta[c] - mu * scale;
  }
  __syncthreads();
  int r = blockIdx.x * 4 + wv;
  const float* src = emb + (long)r * 512 + lane * 8;
  f32x4 x0 = *(const f32x4*)src;
  f32x4 x1 = *(const f32x4*)(src + 4);
  float vals[8]; float sq = 0.f;
  int c0 = lane * 8;
#pragma unroll
  for (int j = 0; j < 4; ++j) {
    vals[j] = fmaf(x0[j], ssl[c0 + j], ssl[512 + c0 + j]);
    vals[4 + j] = fmaf(x1[j], ssl[c0 + 4 + j], ssl[512 + c0 + 4 + j]);
  }
#pragma unroll
  for (int j = 0; j < 8; ++j) sq = fmaf(vals[j], vals[j], sq);
  short8 o;
#pragma unroll
  for (int j = 0; j < 8; ++j) o[j] = f2bf(vals[j]);
  *(short8*)(vbf + (long)r * 512 + c0) = o;
#pragma unroll
  for (int off = 1; off < 64; off <<= 1) sq += __shfl_xor(sq, off);
  float inv = 1.f / (sqrtf(sq) + 1e-8f);
  f32x4 o0, o1;
#pragma unroll
  for (int j = 0; j < 4; ++j) { o0[j] = vals[j] * inv; o1[j] = vals[4 + j] * inv; }
  *(f32x4*)(vn + (long)r * 512 + c0) = o0;
  *(f32x4*)(vn + (long)r * 512 + c0 + 4) = o1;
}

// ---------------- fused GEMM+sim: [0,32) hv ; [32,288) sim ; [288,2336) hx ----------------
// LDS (34816 B): [0,16384) As | [16384,32768) Bs | [32768,34816) csw
// sim aliases: a[16][132] at 0, b[16][132] at 8448.
#define ASP  ((short*)(smem))
#define BSP  ((short*)(smem + 16384))
#define CSW  ((float(*)[2][128])(smem + 32768))
#define SIMA ((float(*)[132])(smem))
#define SIMB ((float(*)[132])(smem + 8448))

__global__ __launch_bounds__(256, 3) void k_gemm(
    const float* __restrict__ x, const short* __restrict__ Wxt,
    const short* __restrict__ vbf, const short* __restrict__ Wvt,
    const float* __restrict__ vn,
    short* __restrict__ Cbf, float* __restrict__ hvr, float* __restrict__ simP,
    float* __restrict__ pstatsX, float* __restrict__ pstatsV) {
  __shared__ char smem[34816];
  int tid = threadIdx.x, lane = tid & 63, wave = tid >> 6;
  int wr = (wave >> 1) * 64, wc = (wave & 1) * 64;

  if (blockIdx.x >= 32 && blockIdx.x < 288) {
    // ---- sim: 128x128 tiles, 8x8/thread, 4-way k-split, k-major LDS ----
    int sid = blockIdx.x - 32;
    int tile = sid >> 2, kh = sid & 3;
    int i0 = (tile >> 3) * 128, j0 = (tile & 7) * 128;
    int row2 = tid >> 1, kg = (tid & 1) * 8;
    int tr = tid >> 4, tc = tid & 15;
    float acc[8][8] = {};
    for (int k0 = kh * 128; k0 < kh * 128 + 128; k0 += 16) {
      __syncthreads();
      f32x4 va0 = *(const f32x4*)(vn + (long)(i0 + row2) * 512 + k0 + kg);
      f32x4 va1 = *(const f32x4*)(vn + (long)(i0 + row2) * 512 + k0 + kg + 4);
      f32x4 vb0 = *(const f32x4*)(vn + (long)(j0 + row2) * 512 + k0 + kg);
      f32x4 vb1 = *(const f32x4*)(vn + (long)(j0 + row2) * 512 + k0 + kg + 4);
#pragma unroll
      for (int j = 0; j < 4; ++j) {
        SIMA[kg + j][row2] = va0[j]; SIMA[kg + 4 + j][row2] = va1[j];
        SIMB[kg + j][row2] = vb0[j]; SIMB[kg + 4 + j][row2] = vb1[j];
      }
      __syncthreads();
#pragma unroll
      for (int k = 0; k < 16; ++k) {
        f32x4 ar0 = *(const f32x4*)&SIMA[k][tr * 8];
        f32x4 ar1 = *(const f32x4*)&SIMA[k][tr * 8 + 4];
        f32x4 br0 = *(const f32x4*)&SIMB[k][tc * 8];
        f32x4 br1 = *(const f32x4*)&SIMB[k][tc * 8 + 4];
        float ar[8], br[8];
#pragma unroll
        for (int j = 0; j < 4; ++j) { ar[j] = ar0[j]; ar[4 + j] = ar1[j]; br[j] = br0[j]; br[4 + j] = br1[j]; }
#pragma unroll
        for (int i = 0; i < 8; ++i)
#pragma unroll
          for (int j = 0; j < 8; ++j)
            acc[i][j] = fmaf(ar[i], br[j], acc[i][j]);
      }
    }
    float* dst = simP + (long)kh * 1048576;
#pragma unroll
    for (int i = 0; i < 8; ++i) {
      f32x4 o0, o1;
#pragma unroll
      for (int j = 0; j < 4; ++j) { o0[j] = acc[i][j]; o1[j] = acc[i][4 + j]; }
      float* rowp = dst + (long)(i0 + tr * 8 + i) * 1024 + j0 + tc * 8;
      *(f32x4*)rowp = o0;
      *(f32x4*)(rowp + 4) = o1;
    }
    return;
  }

  if (blockIdx.x < 32) {
    // ---- hv path: single-buffered m97 pattern (linearized pointers) ----
    int id = blockIdx.x;                  // mt*8 + nt*2 + mat
    int mt = id >> 3, nt = (id >> 1) & 3, mat = id & 1;
    int m0 = mt * 128, n0 = nt * 128;
    int cB = wave * 256 + lane;
    int rowB = cB >> 3;
    int cclB = (cB & 7) ^ (rowB & 7);
    const short* aB = vbf + ((long)mat * 512 + m0) * 512 + (long)rowB * 512 + cclB * 8;
    const short* bB = Wvt + (long)mat * 262144 + (long)n0 * 512 + (long)rowB * 512 + cclB * 8;
    int lOff = wave * 2048;
    f32x4 acc[4][4] = {};
    for (int t = 0; t < 8; ++t) {
      int kn = t * 64;
      __syncthreads();
#pragma unroll
      for (int i = 0; i < 4; ++i) {
        LDSG(aB + i * 4096 + kn, ASP + lOff + i * 512);
        LDSG(bB + i * 4096 + kn, BSP + lOff + i * 512);
      }
      __syncthreads();
#pragma unroll
      for (int kk = 0; kk < 2; ++kk) {
        int k0 = kk * 32 + (lane >> 4) * 8;
        bf16x8 af[4], bfr[4];
#pragma unroll
        for (int m = 0; m < 4; ++m) {
          int row = wr + m * 16 + (lane & 15);
          int boff = (row * 128 + k0 * 2) ^ ((row & 7) << 4);
          af[m] = *reinterpret_cast<const bf16x8*>((const char*)ASP + boff);
        }
#pragma unroll
        for (int n = 0; n < 4; ++n) {
          int row = wc + n * 16 + (lane & 15);
          int boff = (row * 128 + k0 * 2) ^ ((row & 7) << 4);
          bfr[n] = *reinterpret_cast<const bf16x8*>((const char*)BSP + boff);
        }
#pragma unroll
        for (int m = 0; m < 4; ++m)
#pragma unroll
          for (int n = 0; n < 4; ++n)
            acc[m][n] = __builtin_amdgcn_mfma_f32_16x16x32_bf16(af[m], bfr[n], acc[m][n], 0, 0, 0);
      }
    }
    float* Cb = hvr + (long)mat * 262144;
#pragma unroll
    for (int n = 0; n < 4; ++n) {
      int col = n0 + wc + n * 16 + (lane & 15);
      float s = 0.f, q = 0.f;
#pragma unroll
      for (int m = 0; m < 4; ++m) {
        int row = m0 + wr + m * 16 + ((lane >> 4) << 2);
#pragma unroll
        for (int j = 0; j < 4; ++j) {
          float v = acc[m][n][j];
          s += v; q = fmaf(v, v, q);
          Cb[(long)(row + j) * 512 + col] = v;
        }
      }
      s += __shfl_xor(s, 16); s += __shfl_xor(s, 32);
      q += __shfl_xor(q, 16); q += __shfl_xor(q, 32);
      if (lane < 16) {
        CSW[0][wave >> 1][wc + n * 16 + lane] = s;
        CSW[1][wave >> 1][wc + n * 16 + lane] = q;
      }
    }
    __syncthreads();
    {
      int v = tid >> 7, cl = tid & 127;
      pstatsV[(((long)mat * 4 + mt) * 2 + v) * 512 + n0 + cl] =
          CSW[v][0][cl] + CSW[v][1][cl];
    }
    return;
  }

  // ---- hx path: single-buffer, early A-reg issue (linearized pointers) ----
  int id = blockIdx.x - 288;
  int w = (id & 7) * 256 + (id >> 3);   // XCD-chunked
  int mt = w >> 3, rres = w & 7;
  int nt = rres & 3, mat = rres >> 2;
  int m0 = mt * 128, n0 = nt * 128;

  int rowA = tid >> 3, gA = tid & 7;
  int rrA = m0 + rowA;
  int bA = rrA >> 9, pA = rrA & 511;
  const float* aBase = x + ((long)(bA * 1024 + mat * 512 + pA)) * 512 + gA * 8;
  int aOff0 = (rowA * 128 + gA * 16) ^ ((rowA & 7) << 4);
  int cB = wave * 256 + lane;
  int rowB = cB >> 3;
  int cclB = (cB & 7) ^ (rowB & 7);
  const short* bBase = Wxt + (long)mat * 262144 + (long)n0 * 512 + (long)rowB * 512 + cclB * 8;
  int bLds0 = wave * 2048;

  f32x4 acc[4][4] = {};
  f32x4 a0[4], a1[4];
#pragma unroll
  for (int i = 0; i < 4; ++i) {
    a0[i] = *(const f32x4*)(aBase + i * 16384);
    a1[i] = *(const f32x4*)(aBase + i * 16384 + 4);
  }

  for (int t = 0; t < 8; ++t) {
    __syncthreads();
#pragma unroll
    for (int i = 0; i < 4; ++i) LDSG(bBase + i * 4096 + t * 64, BSP + bLds0 + i * 512);
#pragma unroll
    for (int i = 0; i < 4; ++i) {
      short8 o;
#pragma unroll
      for (int j = 0; j < 4; ++j) { o[j] = f2bf(a0[i][j]); o[4 + j] = f2bf(a1[i][j]); }
      *(short8*)((char*)ASP + aOff0 + i * 4096) = o;
    }
    __syncthreads();
    if (t < 7) {
      int kn = (t + 1) * 64;
#pragma unroll
      for (int i = 0; i < 4; ++i) {
        a0[i] = *(const f32x4*)(aBase + i * 16384 + kn);
        a1[i] = *(const f32x4*)(aBase + i * 16384 + kn + 4);
      }
    }
#pragma unroll
    for (int kk = 0; kk < 2; ++kk) {
      int k0 = kk * 32 + (lane >> 4) * 8;
      bf16x8 af[4], bfr[4];
#pragma unroll
      for (int m = 0; m < 4; ++m) {
        int row = wr + m * 16 + (lane & 15);
        int boff = (row * 128 + k0 * 2) ^ ((row & 7) << 4);
        af[m] = *reinterpret_cast<const bf16x8*>((const char*)ASP + boff);
      }
#pragma unroll
      for (int n = 0; n < 4; ++n) {
        int row = wc + n * 16 + (lane & 15);
        int boff = (row * 128 + k0 * 2) ^ ((row & 7) << 4);
        bfr[n] = *reinterpret_cast<const bf16x8*>((const char*)BSP + boff);
      }
#pragma unroll
      for (int m = 0; m < 4; ++m)
#pragma unroll
        for (int n = 0; n < 4; ++n)
          acc[m][n] = __builtin_amdgcn_mfma_f32_16x16x32_bf16(af[m], bfr[n], acc[m][n], 0, 0, 0);
    }
  }
  short* Cb = Cbf + (long)mat * 32768 * 512;
#pragma unroll
  for (int n = 0; n < 4; ++n) {
    int col = n0 + wc + n * 16 + (lane & 15);
    float s = 0.f, q = 0.f;
#pragma unroll
    for (int m = 0; m < 4; ++m) {
      int row = m0 + wr + m * 16 + ((lane >> 4) << 2);
#pragma unroll
      for (int j = 0; j < 4; ++j) {
        float v = acc[m][n][j];
        s += v; q = fmaf(v, v, q);
        Cb[(long)(row + j) * 512 + col] = f2bf(v);
      }
    }
    s += __shfl_xor(s, 16); s += __shfl_xor(s, 32);
    q += __shfl_xor(q, 16); q += __shfl_xor(q, 32);
    if (lane < 16) {
      CSW[0][wave >> 1][wc + n * 16 + lane] = s;
      CSW[1][wave >> 1][wc + n * 16 + lane] = q;
    }
  }
  __syncthreads();
  {
    int v = tid >> 7, cl = tid & 127;
    pstatsX[(((long)mat * 256 + mt) * 2 + v) * 512 + n0 + cl] =
        CSW[v][0][cl] + CSW[v][1][cl];
  }
}

// ---------------- reduce X and V partials -> ssX, ssV ----------------
__global__ void k_colreduceXV(const float* __restrict__ pstatsX,
                              const float* __restrict__ pstatsV,
                              const float* __restrict__ gx_g, const float* __restrict__ gx_b,
                              const float* __restrict__ gv_g, const float* __restrict__ gv_b,
                              float* __restrict__ ssX, float* __restrict__ ssV) {
  int which = blockIdx.y;
  int c = blockIdx.x * 256 + threadIdx.x;
  if (which < 2) {
    int mat = which;
    float s = 0.f, q = 0.f;
    for (int k = 0; k < 256; ++k) {
      s += pstatsX[(((long)mat * 256 + k) * 2 + 0) * 512 + c];
      q += pstatsX[(((long)mat * 256 + k) * 2 + 1) * 512 + c];
    }
    float mu = s * (1.f / 32768.f);
    float var = fmaxf(q * (1.f / 32768.f) - mu * mu, 0.f);
    float scale = rsqrtf(var + 1e-5f) * gx_g[(long)mat * 512 + c];
    ssX[(mat * 2 + 0) * 512 + c] = scale;
    ssX[(mat * 2 + 1) * 512 + c] = gx_b[(long)mat * 512 + c] - mu * scale;
  } else {
    int mat = which - 2;
    float s = 0.f, q = 0.f;
    for (int k = 0; k < 4; ++k) {
      s += pstatsV[(((long)mat * 4 + k) * 2 + 0) * 512 + c];
      q += pstatsV[(((long)mat * 4 + k) * 2 + 1) * 512 + c];
    }
    float mu = s * (1.f / 512.f);
    float var = fmaxf(q * (1.f / 512.f) - mu * mu, 0.f);
    float scale = rsqrtf(var + 1e-5f) * gv_g[(long)mat * 512 + c];
    ssV[(mat * 2 + 0) * 512 + c] = scale;
    ssV[(mat * 2 + 1) * 512 + c] = gv_b[(long)mat * 512 + c] - mu * scale;
  }
}

// ---------------- fused finalize: [0,256) topk ; [256,1280) hv-bcast ; rest hx ----------------
__global__ __launch_bounds__(256) void k_final(
    const short* __restrict__ Cbf, const float* __restrict__ ssX,
    const float* __restrict__ hvr, const float* __restrict__ ssV,
    const float* __restrict__ simP, float* __restrict__ out) {
  int bid = blockIdx.x, tid = threadIdx.x;
  if (bid < 256) {
    // ---- topk: one wave per row ----
    int wv = tid >> 6, lane = tid & 63;
    int row = bid * 4 + wv;
    const float* r0 = simP + (long)row * 1024;
    f32x4 v[4];
#pragma unroll
    for (int i = 0; i < 4; ++i) {
      f32x4 s = *(const f32x4*)(r0 + i * 256 + lane * 4);
#pragma unroll
      for (int h = 1; h < 4; ++h)
        s += *(const f32x4*)(r0 + (long)h * 1048576 + i * 256 + lane * 4);
      v[i] = s;
    }
    float* outIdx = out + 131072L * 512;
    for (int it = 0; it < 30; ++it) {
      float bv = -1e30f; int bi = 1 << 30;
#pragma unroll
      for (int i = 0; i < 4; ++i)
#pragma unroll
        for (int j = 0; j < 4; ++j) {
          float val = v[i][j];
          if (val > bv) { bv = val; bi = i * 256 + lane * 4 + j; }
        }
#pragma unroll
      for (int off = 1; off < 64; off <<= 1) {
        float ov = __shfl_xor(bv, off);
        int oi = __shfl_xor(bi, off);
        if (ov > bv || (ov == bv && oi < bi)) { bv = ov; bi = oi; }
      }
      if (lane == 0) outIdx[(long)row * 30 + it] = (float)bi;
#pragma unroll
      for (int i = 0; i < 4; ++i)
#pragma unroll
        for (int j = 0; j < 4; ++j)
          if ((i * 256 + lane * 4 + j) == bi) v[i][j] = -1e30f;
    }
  } else if (bid < 1280) {
    // ---- hv broadcast: 1024 blocks, each one (mat,b) x 64-row slice (128 KB) ----
    int b_ = bid - 256;
    int mat = b_ >> 9, rem = b_ & 511;
    int bb = rem >> 3, seg = rem & 7;
    int d = (tid & 127) * 4, pr = tid >> 7;
    f32x4 sc = *(const f32x4*)(ssV + ((long)mat * 2 + 0) * 512 + d);
    f32x4 sh = *(const f32x4*)(ssV + ((long)mat * 2 + 1) * 512 + d);
    const float* src = hvr + (long)mat * 262144;
    float* dst = out + 65536L * 512 + ((long)(mat * 64 + bb)) * 262144;
    int pbase = seg * 64 + pr;
#pragma unroll 4
    for (int k = 0; k < 32; ++k) {
      int p = pbase + k * 2;
      f32x4 h = *(const f32x4*)(src + (long)p * 512 + d);
      f32x4 o;
#pragma unroll
      for (int j = 0; j < 4; ++j) o[j] = fmaf(h[j], sc[j], sh[j]);
      *(f32x4*)(dst + (long)p * 512 + d) = o;
    }
  } else {
    // ---- hx finalize: bf16 -> BN -> f32 ----
    long e = (long)(bid - 1280) * 256 + tid;   // 8-elem chunk
    long row = e >> 6;
    int c0 = (int)(e & 63) * 8;
    int mat = (int)(row >> 15);
    short8 h = *(const short8*)(Cbf + row * 512 + c0);
    const float* sb = ssX + mat * 1024;
    f32x4 o0, o1;
#pragma unroll
    for (int j = 0; j < 4; ++j) o0[j] = fmaf(bf2f(h[j]), sb[c0 + j], sb[512 + c0 + j]);
#pragma unroll
    for (int j = 0; j < 4; ++j) o1[j] = fmaf(bf2f(h[4 + j]), sb[c0 + 4 + j], sb[512 + c0 + 4 + j]);
    *(f32x4*)(out + row * 512 + c0) = o0;
    *(f32x4*)(out + row * 512 + c0 + 4) = o1;
  }
}

extern "C" void kernel_launch(void* const* d_in, const int* in_sizes, int n_in,
                              void* d_out, int out_size, void* d_ws, size_t ws_size,
                              hipStream_t stream) {
  (void)in_sizes; (void)n_in; (void)out_size; (void)ws_size;
  const float* x     = (const float*)d_in[0];
  const float* emb   = (const float*)d_in[1];
  const float* emb_g = (const float*)d_in[2];
  const float* emb_b = (const float*)d_in[3];
  const float* Wx    = (const float*)d_in[4];
  // d_in[5] = bx : cancels in BN
  const float* gx_g  = (const float*)d_in[6];
  const float* gx_b  = (const float*)d_in[7];
  const float* Wv    = (const float*)d_in[8];
  // d_in[9] = bv : cancels in BN
  const float* gv_g  = (const float*)d_in[10];
  const float* gv_b  = (const float*)d_in[11];
  float* out = (float*)d_out;

  char* ws = (char*)d_ws;
  short* hxr = (short*)ws;  ws += 65536L * 512 * 2;       // 67.1 MB
  short* Wxt = (short*)ws;  ws += 2L * 512 * 512 * 2;
  short* Wvt = (short*)ws;  ws += 2L * 512 * 512 * 2;
  short* vbf = (short*)ws;  ws += 1024L * 512 * 2;
  float* vn  = (float*)ws;  ws += 1024L * 512 * 4;
  float* hvr = (float*)ws;  ws += 2L * 512 * 512 * 4;
  float* simP = (float*)ws; ws += 4L * 1024 * 1024 * 4;   // 16 MB
  float* pstatsX = (float*)ws; ws += 2L * 256 * 2 * 512 * 4;
  float* pstatsE = (float*)ws; ws += 16L * 2 * 512 * 4;
  float* pstatsV = (float*)ws; ws += 2L * 4 * 2 * 512 * 4;
  float* ssX = (float*)ws;     ws += 4L * 512 * 4;
  float* ssV = (float*)ws;     ws += 4L * 512 * 4;

  k_prep<<<272, 256, 0, stream>>>(Wx, Wv, emb, Wxt, Wvt, pstatsE);
  k_compute_v<<<256, 256, 0, stream>>>(emb, pstatsE, emb_g, emb_b, vbf, vn);
  k_gemm<<<2336, 256, 0, stream>>>(x, Wxt, vbf, Wvt, vn, hxr, hvr, simP, pstatsX, pstatsV);
  k_colreduceXV<<<dim3(2, 4), 256, 0, stream>>>(pstatsX, pstatsV, gx_g, gx_b, gv_g, gv_b, ssX, ssV);
  // TIMING PROBE: k_final launched twice (idempotent). Delta vs r12 = T_final.
  k_final<<<17664, 256, 0, stream>>>(hxr, ssX, hvr, ssV, simP, out);
  k_final<<<17664, 256, 0, stream>>>(hxr, ssX, hvr, ssV, simP, out);
}

// Round 14
// 181.311 us; speedup vs baseline: 1.6594x; 1.6594x over previous
//
#include <hip/hip_runtime.h>
#include <hip/hip_bf16.h>
#include <cstdint>

// B=64, N=1024, L=512, D=512, T=2, P=512, K_top=30
// out: rows [0,65536) hx ; [65536,131072) hv tiled ; then 1024*30 topk idx (float)

typedef float f32x4 __attribute__((ext_vector_type(4)));
typedef __bf16 bf16x8 __attribute__((ext_vector_type(8)));
typedef short short8 __attribute__((ext_vector_type(8)));
typedef short short4v __attribute__((ext_vector_type(4)));

__device__ __forceinline__ short f2bf(float f) {
  __hip_bfloat16 h = __float2bfloat16(f);   // native RNE cvt
  return *reinterpret_cast<short*>(&h);
}
__device__ __forceinline__ float bf2f(short s) {
  union { unsigned u; float f; } x; x.u = ((unsigned)(unsigned short)s) << 16;
  return x.f;
}

#define LDSG(gp, lp) __builtin_amdgcn_global_load_lds(                     \
    (const __attribute__((address_space(1))) void*)(gp),                   \
    (__attribute__((address_space(3))) void*)(lp), 16, 0, 0)

// ---------------- prep: [0,256) transpose W ; [256,272) emb col-stats ----------------
__global__ __launch_bounds__(256) void k_prep(
    const float* __restrict__ Wx, const float* __restrict__ Wv,
    const float* __restrict__ emb,
    short* __restrict__ Wxt, short* __restrict__ Wvt,
    float* __restrict__ pstatsE) {
  __shared__ float t[64][65];
  int bid = blockIdx.x, tid = threadIdx.x;
  if (bid < 256) {
    int z = bid >> 6, tile = bid & 63;
    const float* W = (z < 2) ? (Wx + (long)z * 262144) : (Wv + (long)(z - 2) * 262144);
    short* Wt = (z < 2) ? (Wxt + (long)z * 262144) : (Wvt + (long)(z - 2) * 262144);
    int r0 = (tile >> 3) * 64, c0 = (tile & 7) * 64;
    int lr = tid >> 4, lc = (tid & 15) * 4;
#pragma unroll
    for (int p = 0; p < 4; ++p) {
      f32x4 v = *(const f32x4*)(W + (long)(r0 + lr + p * 16) * 512 + c0 + lc);
#pragma unroll
      for (int j = 0; j < 4; ++j) t[lr + p * 16][lc + j] = v[j];
    }
    __syncthreads();
    int wr = (tid & 15) * 4;
    int wc = tid >> 4;
#pragma unroll
    for (int p = 0; p < 4; ++p) {
      int c = wc + p * 16;
      short4v o;
#pragma unroll
      for (int j = 0; j < 4; ++j) o[j] = f2bf(t[wr + j][c]);
      *(short4v*)(Wt + (long)(c0 + c) * 512 + r0 + wr) = o;
    }
  } else {
    int chunk = bid - 256;  // 16 chunks x 64 rows
    const float* p = emb + (long)chunk * 64 * 512;
#pragma unroll
    for (int i = 0; i < 2; ++i) {
      int c = tid + i * 256;
      float s = 0.f, q = 0.f;
#pragma unroll 4
      for (int r = 0; r < 64; ++r) {
        float v = p[(long)r * 512 + c];
        s += v; q = fmaf(v, v, q);
      }
      pstatsE[((long)chunk * 2 + 0) * 512 + c] = s;
      pstatsE[((long)chunk * 2 + 1) * 512 + c] = q;
    }
  }
}

// ---------------- v = BN(emb): wave-per-row; vbf bf16; vn normalized ----------------
__global__ __launch_bounds__(256) void k_compute_v(const float* __restrict__ emb,
                                                   const float* __restrict__ pstatsE,
                                                   const float* __restrict__ gamma,
                                                   const float* __restrict__ beta,
                                                   short* __restrict__ vbf,
                                                   float* __restrict__ vn) {
  __shared__ float ssl[1024];
  int tid = threadIdx.x, wv = tid >> 6, lane = tid & 63;
#pragma unroll
  for (int i = 0; i < 2; ++i) {
    int c = tid + i * 256;
    float s = 0.f, q = 0.f;
#pragma unroll
    for (int k = 0; k < 16; ++k) {
      s += pstatsE[((long)k * 2 + 0) * 512 + c];
      q += pstatsE[((long)k * 2 + 1) * 512 + c];
    }
    float mu = s * (1.f / 1024.f);
    float var = fmaxf(q * (1.f / 1024.f) - mu * mu, 0.f);
    float scale = rsqrtf(var + 1e-5f) * gamma[c];
    ssl[c] = scale;
    ssl[512 + c] = beta[c] - mu * scale;
  }
  __syncthreads();
  int r = blockIdx.x * 4 + wv;
  const float* src = emb + (long)r * 512 + lane * 8;
  f32x4 x0 = *(const f32x4*)src;
  f32x4 x1 = *(const f32x4*)(src + 4);
  float vals[8]; float sq = 0.f;
  int c0 = lane * 8;
#pragma unroll
  for (int j = 0; j < 4; ++j) {
    vals[j] = fmaf(x0[j], ssl[c0 + j], ssl[512 + c0 + j]);
    vals[4 + j] = fmaf(x1[j], ssl[c0 + 4 + j], ssl[512 + c0 + 4 + j]);
  }
#pragma unroll
  for (int j = 0; j < 8; ++j) sq = fmaf(vals[j], vals[j], sq);
  short8 o;
#pragma unroll
  for (int j = 0; j < 8; ++j) o[j] = f2bf(vals[j]);
  *(short8*)(vbf + (long)r * 512 + c0) = o;
#pragma unroll
  for (int off = 1; off < 64; off <<= 1) sq += __shfl_xor(sq, off);
  float inv = 1.f / (sqrtf(sq) + 1e-8f);
  f32x4 o0, o1;
#pragma unroll
  for (int j = 0; j < 4; ++j) { o0[j] = vals[j] * inv; o1[j] = vals[4 + j] * inv; }
  *(f32x4*)(vn + (long)r * 512 + c0) = o0;
  *(f32x4*)(vn + (long)r * 512 + c0 + 4) = o1;
}

// ---------------- fused GEMM+sim: [0,32) hv ; [32,288) sim ; [288,2336) hx ----------------
// LDS (34816 B): [0,16384) As | [16384,32768) Bs | [32768,34816) csw
// sim aliases: a[16][132] at 0, b[16][132] at 8448.
#define ASP  ((short*)(smem))
#define BSP  ((short*)(smem + 16384))
#define CSW  ((float(*)[2][128])(smem + 32768))
#define SIMA ((float(*)[132])(smem))
#define SIMB ((float(*)[132])(smem + 8448))

__global__ __launch_bounds__(256, 3) void k_gemm(
    const float* __restrict__ x, const short* __restrict__ Wxt,
    const short* __restrict__ vbf, const short* __restrict__ Wvt,
    const float* __restrict__ vn,
    short* __restrict__ Cbf, float* __restrict__ hvr, float* __restrict__ simP,
    float* __restrict__ pstatsX, float* __restrict__ pstatsV) {
  __shared__ char smem[34816];
  int tid = threadIdx.x, lane = tid & 63, wave = tid >> 6;
  int wr = (wave >> 1) * 64, wc = (wave & 1) * 64;

  if (blockIdx.x >= 32 && blockIdx.x < 288) {
    // ---- sim: 128x128 tiles, 8x8/thread, 4-way k-split, k-major LDS ----
    int sid = blockIdx.x - 32;
    int tile = sid >> 2, kh = sid & 3;
    int i0 = (tile >> 3) * 128, j0 = (tile & 7) * 128;
    int row2 = tid >> 1, kg = (tid & 1) * 8;
    int tr = tid >> 4, tc = tid & 15;
    float acc[8][8] = {};
    for (int k0 = kh * 128; k0 < kh * 128 + 128; k0 += 16) {
      __syncthreads();
      f32x4 va0 = *(const f32x4*)(vn + (long)(i0 + row2) * 512 + k0 + kg);
      f32x4 va1 = *(const f32x4*)(vn + (long)(i0 + row2) * 512 + k0 + kg + 4);
      f32x4 vb0 = *(const f32x4*)(vn + (long)(j0 + row2) * 512 + k0 + kg);
      f32x4 vb1 = *(const f32x4*)(vn + (long)(j0 + row2) * 512 + k0 + kg + 4);
#pragma unroll
      for (int j = 0; j < 4; ++j) {
        SIMA[kg + j][row2] = va0[j]; SIMA[kg + 4 + j][row2] = va1[j];
        SIMB[kg + j][row2] = vb0[j]; SIMB[kg + 4 + j][row2] = vb1[j];
      }
      __syncthreads();
#pragma unroll
      for (int k = 0; k < 16; ++k) {
        f32x4 ar0 = *(const f32x4*)&SIMA[k][tr * 8];
        f32x4 ar1 = *(const f32x4*)&SIMA[k][tr * 8 + 4];
        f32x4 br0 = *(const f32x4*)&SIMB[k][tc * 8];
        f32x4 br1 = *(const f32x4*)&SIMB[k][tc * 8 + 4];
        float ar[8], br[8];
#pragma unroll
        for (int j = 0; j < 4; ++j) { ar[j] = ar0[j]; ar[4 + j] = ar1[j]; br[j] = br0[j]; br[4 + j] = br1[j]; }
#pragma unroll
        for (int i = 0; i < 8; ++i)
#pragma unroll
          for (int j = 0; j < 8; ++j)
            acc[i][j] = fmaf(ar[i], br[j], acc[i][j]);
      }
    }
    float* dst = simP + (long)kh * 1048576;
#pragma unroll
    for (int i = 0; i < 8; ++i) {
      f32x4 o0, o1;
#pragma unroll
      for (int j = 0; j < 4; ++j) { o0[j] = acc[i][j]; o1[j] = acc[i][4 + j]; }
      float* rowp = dst + (long)(i0 + tr * 8 + i) * 1024 + j0 + tc * 8;
      *(f32x4*)rowp = o0;
      *(f32x4*)(rowp + 4) = o1;
    }
    return;
  }

  if (blockIdx.x < 32) {
    // ---- hv path: single-buffered m97 pattern (linearized pointers) ----
    int id = blockIdx.x;                  // mt*8 + nt*2 + mat
    int mt = id >> 3, nt = (id >> 1) & 3, mat = id & 1;
    int m0 = mt * 128, n0 = nt * 128;
    int cB = wave * 256 + lane;
    int rowB = cB >> 3;
    int cclB = (cB & 7) ^ (rowB & 7);
    const short* aB = vbf + ((long)mat * 512 + m0) * 512 + (long)rowB * 512 + cclB * 8;
    const short* bB = Wvt + (long)mat * 262144 + (long)n0 * 512 + (long)rowB * 512 + cclB * 8;
    int lOff = wave * 2048;
    f32x4 acc[4][4] = {};
    for (int t = 0; t < 8; ++t) {
      int kn = t * 64;
      __syncthreads();
#pragma unroll
      for (int i = 0; i < 4; ++i) {
        LDSG(aB + i * 4096 + kn, ASP + lOff + i * 512);
        LDSG(bB + i * 4096 + kn, BSP + lOff + i * 512);
      }
      __syncthreads();
#pragma unroll
      for (int kk = 0; kk < 2; ++kk) {
        int k0 = kk * 32 + (lane >> 4) * 8;
        bf16x8 af[4], bfr[4];
#pragma unroll
        for (int m = 0; m < 4; ++m) {
          int row = wr + m * 16 + (lane & 15);
          int boff = (row * 128 + k0 * 2) ^ ((row & 7) << 4);
          af[m] = *reinterpret_cast<const bf16x8*>((const char*)ASP + boff);
        }
#pragma unroll
        for (int n = 0; n < 4; ++n) {
          int row = wc + n * 16 + (lane & 15);
          int boff = (row * 128 + k0 * 2) ^ ((row & 7) << 4);
          bfr[n] = *reinterpret_cast<const bf16x8*>((const char*)BSP + boff);
        }
#pragma unroll
        for (int m = 0; m < 4; ++m)
#pragma unroll
          for (int n = 0; n < 4; ++n)
            acc[m][n] = __builtin_amdgcn_mfma_f32_16x16x32_bf16(af[m], bfr[n], acc[m][n], 0, 0, 0);
      }
    }
    float* Cb = hvr + (long)mat * 262144;
#pragma unroll
    for (int n = 0; n < 4; ++n) {
      int col = n0 + wc + n * 16 + (lane & 15);
      float s = 0.f, q = 0.f;
#pragma unroll
      for (int m = 0; m < 4; ++m) {
        int row = m0 + wr + m * 16 + ((lane >> 4) << 2);
#pragma unroll
        for (int j = 0; j < 4; ++j) {
          float v = acc[m][n][j];
          s += v; q = fmaf(v, v, q);
          Cb[(long)(row + j) * 512 + col] = v;
        }
      }
      s += __shfl_xor(s, 16); s += __shfl_xor(s, 32);
      q += __shfl_xor(q, 16); q += __shfl_xor(q, 32);
      if (lane < 16) {
        CSW[0][wave >> 1][wc + n * 16 + lane] = s;
        CSW[1][wave >> 1][wc + n * 16 + lane] = q;
      }
    }
    __syncthreads();
    {
      int v = tid >> 7, cl = tid & 127;
      pstatsV[(((long)mat * 4 + mt) * 2 + v) * 512 + n0 + cl] =
          CSW[v][0][cl] + CSW[v][1][cl];
    }
    return;
  }

  // ---- hx path: single-buffer, early A-reg issue (linearized pointers) ----
  int id = blockIdx.x - 288;
  int w = (id & 7) * 256 + (id >> 3);   // XCD-chunked
  int mt = w >> 3, rres = w & 7;
  int nt = rres & 3, mat = rres >> 2;
  int m0 = mt * 128, n0 = nt * 128;

  int rowA = tid >> 3, gA = tid & 7;
  int rrA = m0 + rowA;
  int bA = rrA >> 9, pA = rrA & 511;
  const float* aBase = x + ((long)(bA * 1024 + mat * 512 + pA)) * 512 + gA * 8;
  int aOff0 = (rowA * 128 + gA * 16) ^ ((rowA & 7) << 4);
  int cB = wave * 256 + lane;
  int rowB = cB >> 3;
  int cclB = (cB & 7) ^ (rowB & 7);
  const short* bBase = Wxt + (long)mat * 262144 + (long)n0 * 512 + (long)rowB * 512 + cclB * 8;
  int bLds0 = wave * 2048;

  f32x4 acc[4][4] = {};
  f32x4 a0[4], a1[4];
#pragma unroll
  for (int i = 0; i < 4; ++i) {
    a0[i] = *(const f32x4*)(aBase + i * 16384);
    a1[i] = *(const f32x4*)(aBase + i * 16384 + 4);
  }

  for (int t = 0; t < 8; ++t) {
    __syncthreads();
#pragma unroll
    for (int i = 0; i < 4; ++i) LDSG(bBase + i * 4096 + t * 64, BSP + bLds0 + i * 512);
#pragma unroll
    for (int i = 0; i < 4; ++i) {
      short8 o;
#pragma unroll
      for (int j = 0; j < 4; ++j) { o[j] = f2bf(a0[i][j]); o[4 + j] = f2bf(a1[i][j]); }
      *(short8*)((char*)ASP + aOff0 + i * 4096) = o;
    }
    __syncthreads();
    if (t < 7) {
      int kn = (t + 1) * 64;
#pragma unroll
      for (int i = 0; i < 4; ++i) {
        a0[i] = *(const f32x4*)(aBase + i * 16384 + kn);
        a1[i] = *(const f32x4*)(aBase + i * 16384 + kn + 4);
      }
    }
#pragma unroll
    for (int kk = 0; kk < 2; ++kk) {
      int k0 = kk * 32 + (lane >> 4) * 8;
      bf16x8 af[4], bfr[4];
#pragma unroll
      for (int m = 0; m < 4; ++m) {
        int row = wr + m * 16 + (lane & 15);
        int boff = (row * 128 + k0 * 2) ^ ((row & 7) << 4);
        af[m] = *reinterpret_cast<const bf16x8*>((const char*)ASP + boff);
      }
#pragma unroll
      for (int n = 0; n < 4; ++n) {
        int row = wc + n * 16 + (lane & 15);
        int boff = (row * 128 + k0 * 2) ^ ((row & 7) << 4);
        bfr[n] = *reinterpret_cast<const bf16x8*>((const char*)BSP + boff);
      }
#pragma unroll
      for (int m = 0; m < 4; ++m)
#pragma unroll
        for (int n = 0; n < 4; ++n)
          acc[m][n] = __builtin_amdgcn_mfma_f32_16x16x32_bf16(af[m], bfr[n], acc[m][n], 0, 0, 0);
    }
  }
  short* Cb = Cbf + (long)mat * 32768 * 512;
#pragma unroll
  for (int n = 0; n < 4; ++n) {
    int col = n0 + wc + n * 16 + (lane & 15);
    float s = 0.f, q = 0.f;
#pragma unroll
    for (int m = 0; m < 4; ++m) {
      int row = m0 + wr + m * 16 + ((lane >> 4) << 2);
#pragma unroll
      for (int j = 0; j < 4; ++j) {
        float v = acc[m][n][j];
        s += v; q = fmaf(v, v, q);
        Cb[(long)(row + j) * 512 + col] = f2bf(v);
      }
    }
    s += __shfl_xor(s, 16); s += __shfl_xor(s, 32);
    q += __shfl_xor(q, 16); q += __shfl_xor(q, 32);
    if (lane < 16) {
      CSW[0][wave >> 1][wc + n * 16 + lane] = s;
      CSW[1][wave >> 1][wc + n * 16 + lane] = q;
    }
  }
  __syncthreads();
  {
    int v = tid >> 7, cl = tid & 127;
    pstatsX[(((long)mat * 256 + mt) * 2 + v) * 512 + n0 + cl] =
        CSW[v][0][cl] + CSW[v][1][cl];
  }
}

// ---------------- reduce X and V partials -> ssX, ssV ----------------
__global__ void k_colreduceXV(const float* __restrict__ pstatsX,
                              const float* __restrict__ pstatsV,
                              const float* __restrict__ gx_g, const float* __restrict__ gx_b,
                              const float* __restrict__ gv_g, const float* __restrict__ gv_b,
                              float* __restrict__ ssX, float* __restrict__ ssV) {
  int which = blockIdx.y;
  int c = blockIdx.x * 256 + threadIdx.x;
  if (which < 2) {
    int mat = which;
    float s = 0.f, q = 0.f;
    for (int k = 0; k < 256; ++k) {
      s += pstatsX[(((long)mat * 256 + k) * 2 + 0) * 512 + c];
      q += pstatsX[(((long)mat * 256 + k) * 2 + 1) * 512 + c];
    }
    float mu = s * (1.f / 32768.f);
    float var = fmaxf(q * (1.f / 32768.f) - mu * mu, 0.f);
    float scale = rsqrtf(var + 1e-5f) * gx_g[(long)mat * 512 + c];
    ssX[(mat * 2 + 0) * 512 + c] = scale;
    ssX[(mat * 2 + 1) * 512 + c] = gx_b[(long)mat * 512 + c] - mu * scale;
  } else {
    int mat = which - 2;
    float s = 0.f, q = 0.f;
    for (int k = 0; k < 4; ++k) {
      s += pstatsV[(((long)mat * 4 + k) * 2 + 0) * 512 + c];
      q += pstatsV[(((long)mat * 4 + k) * 2 + 1) * 512 + c];
    }
    float mu = s * (1.f / 512.f);
    float var = fmaxf(q * (1.f / 512.f) - mu * mu, 0.f);
    float scale = rsqrtf(var + 1e-5f) * gv_g[(long)mat * 512 + c];
    ssV[(mat * 2 + 0) * 512 + c] = scale;
    ssV[(mat * 2 + 1) * 512 + c] = gv_b[(long)mat * 512 + c] - mu * scale;
  }
}

// ---------------- fused finalize: [0,256) topk ; [256,1280) hv-bcast ; rest hx ----------------
// Non-temporal loads/stores: all streams here are read-once / write-once.
__global__ __launch_bounds__(256) void k_final(
    const short* __restrict__ Cbf, const float* __restrict__ ssX,
    const float* __restrict__ hvr, const float* __restrict__ ssV,
    const float* __restrict__ simP, float* __restrict__ out) {
  int bid = blockIdx.x, tid = threadIdx.x;
  if (bid < 256) {
    // ---- topk: one wave per row ----
    int wv = tid >> 6, lane = tid & 63;
    int row = bid * 4 + wv;
    const float* r0 = simP + (long)row * 1024;
    f32x4 v[4];
#pragma unroll
    for (int i = 0; i < 4; ++i) {
      f32x4 s = __builtin_nontemporal_load((const f32x4*)(r0 + i * 256 + lane * 4));
#pragma unroll
      for (int h = 1; h < 4; ++h)
        s += __builtin_nontemporal_load((const f32x4*)(r0 + (long)h * 1048576 + i * 256 + lane * 4));
      v[i] = s;
    }
    float* outIdx = out + 131072L * 512;
    for (int it = 0; it < 30; ++it) {
      float bv = -1e30f; int bi = 1 << 30;
#pragma unroll
      for (int i = 0; i < 4; ++i)
#pragma unroll
        for (int j = 0; j < 4; ++j) {
          float val = v[i][j];
          if (val > bv) { bv = val; bi = i * 256 + lane * 4 + j; }
        }
#pragma unroll
      for (int off = 1; off < 64; off <<= 1) {
        float ov = __shfl_xor(bv, off);
        int oi = __shfl_xor(bi, off);
        if (ov > bv || (ov == bv && oi < bi)) { bv = ov; bi = oi; }
      }
      if (lane == 0) outIdx[(long)row * 30 + it] = (float)bi;
#pragma unroll
      for (int i = 0; i < 4; ++i)
#pragma unroll
        for (int j = 0; j < 4; ++j)
          if ((i * 256 + lane * 4 + j) == bi) v[i][j] = -1e30f;
    }
  } else if (bid < 1280) {
    // ---- hv broadcast: 1024 blocks, each one (mat,b) x 64-row slice (128 KB) ----
    int b_ = bid - 256;
    int mat = b_ >> 9, rem = b_ & 511;
    int bb = rem >> 3, seg = rem & 7;
    int d = (tid & 127) * 4, pr = tid >> 7;
    f32x4 sc = *(const f32x4*)(ssV + ((long)mat * 2 + 0) * 512 + d);
    f32x4 sh = *(const f32x4*)(ssV + ((long)mat * 2 + 1) * 512 + d);
    const float* src = hvr + (long)mat * 262144;
    float* dst = out + 65536L * 512 + ((long)(mat * 64 + bb)) * 262144;
    int pbase = seg * 64 + pr;
#pragma unroll 4
    for (int k = 0; k < 32; ++k) {
      int p = pbase + k * 2;
      f32x4 h = *(const f32x4*)(src + (long)p * 512 + d);
      f32x4 o;
#pragma unroll
      for (int j = 0; j < 4; ++j) o[j] = fmaf(h[j], sc[j], sh[j]);
      __builtin_nontemporal_store(o, (f32x4*)(dst + (long)p * 512 + d));
    }
  } else {
    // ---- hx finalize: bf16 -> BN -> f32 ----
    long e = (long)(bid - 1280) * 256 + tid;   // 8-elem chunk
    long row = e >> 6;
    int c0 = (int)(e & 63) * 8;
    int mat = (int)(row >> 15);
    short8 h = __builtin_nontemporal_load((const short8*)(Cbf + row * 512 + c0));
    const float* sb = ssX + mat * 1024;
    f32x4 o0, o1;
#pragma unroll
    for (int j = 0; j < 4; ++j) o0[j] = fmaf(bf2f(h[j]), sb[c0 + j], sb[512 + c0 + j]);
#pragma unroll
    for (int j = 0; j < 4; ++j) o1[j] = fmaf(bf2f(h[4 + j]), sb[c0 + 4 + j], sb[512 + c0 + 4 + j]);
    __builtin_nontemporal_store(o0, (f32x4*)(out + row * 512 + c0));
    __builtin_nontemporal_store(o1, (f32x4*)(out + row * 512 + c0 + 4));
  }
}

extern "C" void kernel_launch(void* const* d_in, const int* in_sizes, int n_in,
                              void* d_out, int out_size, void* d_ws, size_t ws_size,
                              hipStream_t stream) {
  (void)in_sizes; (void)n_in; (void)out_size; (void)ws_size;
  const float* x     = (const float*)d_in[0];
  const float* emb   = (const float*)d_in[1];
  const float* emb_g = (const float*)d_in[2];
  const float* emb_b = (const float*)d_in[3];
  const float* Wx    = (const float*)d_in[4];
  // d_in[5] = bx : cancels in BN
  const float* gx_g  = (const float*)d_in[6];
  const float* gx_b  = (const float*)d_in[7];
  const float* Wv    = (const float*)d_in[8];
  // d_in[9] = bv : cancels in BN
  const float* gv_g  = (const float*)d_in[10];
  const float* gv_b  = (const float*)d_in[11];
  float* out = (float*)d_out;

  char* ws = (char*)d_ws;
  short* hxr = (short*)ws;  ws += 65536L * 512 * 2;       // 67.1 MB
  short* Wxt = (short*)ws;  ws += 2L * 512 * 512 * 2;
  short* Wvt = (short*)ws;  ws += 2L * 512 * 512 * 2;
  short* vbf = (short*)ws;  ws += 1024L * 512 * 2;
  float* vn  = (float*)ws;  ws += 1024L * 512 * 4;
  float* hvr = (float*)ws;  ws += 2L * 512 * 512 * 4;
  float* simP = (float*)ws; ws += 4L * 1024 * 1024 * 4;   // 16 MB
  float* pstatsX = (float*)ws; ws += 2L * 256 * 2 * 512 * 4;
  float* pstatsE = (float*)ws; ws += 16L * 2 * 512 * 4;
  float* pstatsV = (float*)ws; ws += 2L * 4 * 2 * 512 * 4;
  float* ssX = (float*)ws;     ws += 4L * 512 * 4;
  float* ssV = (float*)ws;     ws += 4L * 512 * 4;

  k_prep<<<272, 256, 0, stream>>>(Wx, Wv, emb, Wxt, Wvt, pstatsE);
  k_compute_v<<<256, 256, 0, stream>>>(emb, pstatsE, emb_g, emb_b, vbf, vn);
  k_gemm<<<2336, 256, 0, stream>>>(x, Wxt, vbf, Wvt, vn, hxr, hvr, simP, pstatsX, pstatsV);
  k_colreduceXV<<<dim3(2, 4), 256, 0, stream>>>(pstatsX, pstatsV, gx_g, gx_b, gv_g, gv_b, ssX, ssV);
  k_final<<<17664, 256, 0, stream>>>(hxr, ssX, hvr, ssV, simP, out);
}